// Round 14
// baseline (1132.165 us; speedup 1.0000x reference)
//
#include <hip/hip_runtime.h>
#include <cmath>

#define B_  16
#define SEQ 2048
#define DIM 1024

typedef short  short8 __attribute__((ext_vector_type(8)));
typedef short  sh4    __attribute__((ext_vector_type(4)));
typedef float  f32x4  __attribute__((ext_vector_type(4)));

__device__ __forceinline__ unsigned short f2bf(float x) {
  unsigned u = __builtin_bit_cast(unsigned, x);
  return (unsigned short)((u + 0x7fffu + ((u >> 16) & 1u)) >> 16);   // RNE
}
__device__ __forceinline__ float bf2f(unsigned short h) {
  unsigned u = ((unsigned)h) << 16;
  return __builtin_bit_cast(float, u);
}

__device__ __forceinline__ void gl16(const void* g, void* l) {
  __builtin_amdgcn_global_load_lds(
      (const __attribute__((address_space(1))) void*)g,
      (__attribute__((address_space(3))) void*)l, 16, 0, 0);
}

// ---------------------------------------------------------------------------
// cvt_split: f32 [B*SEQ*DIM] -> bf16 hi/lo planes (context AND query)
// ---------------------------------------------------------------------------
__global__ __launch_bounds__(256) void cvt_split(const float* __restrict__ X,
                                                 unsigned short* __restrict__ hi,
                                                 unsigned short* __restrict__ lo) {
  const size_t N8 = (size_t)B_ * SEQ * DIM / 8;
  for (size_t i = (size_t)blockIdx.x * 256 + threadIdx.x; i < N8;
       i += (size_t)gridDim.x * 256) {
    const size_t base = i * 8;
    float4 a = *(const float4*)&X[base];
    float4 c = *(const float4*)&X[base + 4];
    const float xs[8] = {a.x, a.y, a.z, a.w, c.x, c.y, c.z, c.w};
    short8 h, l;
#pragma unroll
    for (int j = 0; j < 8; ++j) {
      unsigned short hh = f2bf(xs[j]);
      h[j] = (short)hh;
      l[j] = (short)f2bf(xs[j] - bf2f(hh));
    }
    *(short8*)&hi[base] = h;
    *(short8*)&lo[base] = l;
  }
}

// ---------------------------------------------------------------------------
// cvt_w: W[d][e] f32 -> wh[d][e], wl[d][e] bf16 hi/lo (pure split)
// ---------------------------------------------------------------------------
__global__ __launch_bounds__(256) void cvt_w(const float* __restrict__ X,
                                             unsigned short* __restrict__ hi,
                                             unsigned short* __restrict__ lo) {
  const size_t N8 = (size_t)DIM * DIM / 8;
  for (size_t i = (size_t)blockIdx.x * 256 + threadIdx.x; i < N8;
       i += (size_t)gridDim.x * 256) {
    const size_t base = i * 8;
    float4 a = *(const float4*)&X[base];
    float4 c = *(const float4*)&X[base + 4];
    const float xs[8] = {a.x, a.y, a.z, a.w, c.x, c.y, c.z, c.w};
    short8 h, l;
#pragma unroll
    for (int j = 0; j < 8; ++j) {
      unsigned short hh = f2bf(xs[j]);
      h[j] = (short)hh;
      l[j] = (short)f2bf(xs[j] - bf2f(hh));
    }
    *(short8*)&hi[base] = h;
    *(short8*)&lo[base] = l;
  }
}

// ---------------------------------------------------------------------------
// t_chi: ctxT[b][d][s] = transpose of chi[b][s][d]  (bf16 -> bf16, via LDS)
// ---------------------------------------------------------------------------
__global__ __launch_bounds__(256) void t_chi(const unsigned short* __restrict__ H,
                                             unsigned short* __restrict__ T) {
  __shared__ unsigned short L[64][72];
  const int t = threadIdx.x;
  const int d0 = blockIdx.x * 64, s0 = blockIdx.y * 64, b = blockIdx.z;
  const int sl = t >> 2, dp = (t & 3) * 16;
  short8 v0 = *(const short8*)&H[((size_t)b * SEQ + s0 + sl) * DIM + d0 + dp];
  short8 v1 = *(const short8*)&H[((size_t)b * SEQ + s0 + sl) * DIM + d0 + dp + 8];
  *(short8*)&L[sl][dp] = v0;
  *(short8*)&L[sl][dp + 8] = v1;
  __syncthreads();
  const int dl = t >> 2, sp = (t & 3) * 16;
  short8 o0, o1;
#pragma unroll
  for (int k = 0; k < 8; ++k) {
    o0[k] = (short)L[sp + k][dl];
    o1[k] = (short)L[sp + 8 + k][dl];
  }
  *(short8*)&T[((size_t)b * DIM + d0 + dl) * SEQ + s0 + sp] = o0;
  *(short8*)&T[((size_t)b * DIM + d0 + dl) * SEQ + s0 + sp + 8] = o1;
}

// ---------------------------------------------------------------------------
// G1 (m97-clone): z[r][d] = sum_e q[r][e] * W[d][e], 4 planes pure-gl16.
// ---------------------------------------------------------------------------
#define G1GRID 2048    // 256 m-tiles x 8 n-tiles
__global__ __launch_bounds__(256) void g1_z(const unsigned short* __restrict__ qh,
                                            const unsigned short* __restrict__ ql,
                                            const unsigned short* __restrict__ wh,
                                            const unsigned short* __restrict__ wl,
                                            unsigned short* __restrict__ zhi,
                                            unsigned short* __restrict__ zlo) {
  __shared__ unsigned short Ah[128 * 32], Al[128 * 32];
  __shared__ unsigned short Bh[128 * 32], Bl[128 * 32];
  const int tid = threadIdx.x, lane = tid & 63, wave = tid >> 6;

  const int lin = blockIdx.x;
  const int swz = (lin & 7) * (G1GRID / 8) + (lin >> 3);
  const int m0 = (swz >> 3) * 128;
  const int n0 = (swz & 7) * 128;

  const int wm = (wave >> 1) * 64;   // m (z-row)
  const int wn = (wave & 1) * 64;    // n (d)

  const int r_sub = lane >> 2;
  const int c_sub = (((lane & 3) ^ ((lane >> 3) & 3))) * 8;

  f32x4 acc[4][4];
#pragma unroll
  for (int i = 0; i < 4; ++i)
#pragma unroll
    for (int j = 0; j < 4; ++j) acc[i][j] = (f32x4){0.f, 0.f, 0.f, 0.f};

  for (int kc = 0; kc < DIM; kc += 32) {
    if (wave == 0) {
#pragma unroll
      for (int it = 0; it < 8; ++it)
        gl16(&qh[(size_t)(m0 + it * 16 + r_sub) * DIM + kc + c_sub], &Ah[it * 512]);
    } else if (wave == 1) {
#pragma unroll
      for (int it = 0; it < 8; ++it)
        gl16(&ql[(size_t)(m0 + it * 16 + r_sub) * DIM + kc + c_sub], &Al[it * 512]);
    } else if (wave == 2) {
#pragma unroll
      for (int it = 0; it < 8; ++it)
        gl16(&wh[(size_t)(n0 + it * 16 + r_sub) * DIM + kc + c_sub], &Bh[it * 512]);
    } else {
#pragma unroll
      for (int it = 0; it < 8; ++it)
        gl16(&wl[(size_t)(n0 + it * 16 + r_sub) * DIM + kc + c_sub], &Bl[it * 512]);
    }
    __syncthreads();

    short8 ah[4], al[4], bh[4], bl[4];
#pragma unroll
    for (int f = 0; f < 4; ++f) {
      const int ra = wm + f * 16 + (lane & 15);
      const int rb = wn + f * 16 + (lane & 15);
      const int ao = ra * 32 + (((lane >> 4) ^ ((ra >> 1) & 3))) * 8;
      const int bo = rb * 32 + (((lane >> 4) ^ ((rb >> 1) & 3))) * 8;
      ah[f] = *(const short8*)&Ah[ao];  al[f] = *(const short8*)&Al[ao];
      bh[f] = *(const short8*)&Bh[bo];  bl[f] = *(const short8*)&Bl[bo];
    }
#pragma unroll
    for (int i = 0; i < 4; ++i)
#pragma unroll
      for (int j = 0; j < 4; ++j) {
        acc[i][j] = __builtin_amdgcn_mfma_f32_16x16x32_bf16(ah[i], bh[j], acc[i][j], 0, 0, 0);
        acc[i][j] = __builtin_amdgcn_mfma_f32_16x16x32_bf16(al[i], bh[j], acc[i][j], 0, 0, 0);
        acc[i][j] = __builtin_amdgcn_mfma_f32_16x16x32_bf16(ah[i], bl[j], acc[i][j], 0, 0, 0);
      }
    __syncthreads();
  }

#pragma unroll
  for (int i = 0; i < 4; ++i)
#pragma unroll
    for (int j = 0; j < 4; ++j)
#pragma unroll
      for (int r = 0; r < 4; ++r) {
        const int row = m0 + wm + i * 16 + (lane >> 4) * 4 + r;
        const int col = n0 + wn + j * 16 + (lane & 15);
        const float v = acc[i][j][r];
        const unsigned short h = f2bf(v);
        zhi[(size_t)row * DIM + col] = h;
        zlo[(size_t)row * DIM + col] = f2bf(v - bf2f(h));
      }
}

// ---------------------------------------------------------------------------
// G2 (R6-proven, 128x128, 2-barrier, XOR-swizzled): scores = z . ctx^T
// ---------------------------------------------------------------------------
#define G2GRID (16 * 16 * B_)
__global__ __launch_bounds__(256) void g2_scores(const unsigned short* __restrict__ zhi,
                                                 const unsigned short* __restrict__ zlo,
                                                 const unsigned short* __restrict__ chi,
                                                 const unsigned short* __restrict__ clo,
                                                 float* __restrict__ Sc) {
  __shared__ unsigned short Sh[128 * 32], Sl[128 * 32];   // ctx tiles (s-rows)
  __shared__ unsigned short Qh[128 * 32], Ql[128 * 32];   // z tiles (q-rows)
  const int tid = threadIdx.x, lane = tid & 63, wave = tid >> 6;

  const int lin = blockIdx.x;
  const int swz = (lin & 7) * (G2GRID / 8) + (lin >> 3);
  const int s0 = (swz & 15) * 128;
  const int q0 = ((swz >> 4) & 15) * 128;
  const int b  = swz >> 8;

  const int wm = (wave >> 1) * 64;   // s
  const int wn = (wave & 1) * 64;    // q

  const int r_sub = lane >> 2;
  const int c_sub = (((lane & 3) ^ ((lane >> 3) & 3))) * 8;

  f32x4 acc[4][4];
#pragma unroll
  for (int i = 0; i < 4; ++i)
#pragma unroll
    for (int j = 0; j < 4; ++j) acc[i][j] = (f32x4){0.f, 0.f, 0.f, 0.f};

  for (int kc = 0; kc < DIM; kc += 32) {
    if (wave == 0) {
#pragma unroll
      for (int it = 0; it < 8; ++it)
        gl16(&chi[((size_t)b * SEQ + s0 + it * 16 + r_sub) * DIM + kc + c_sub], &Sh[it * 512]);
    } else if (wave == 1) {
#pragma unroll
      for (int it = 0; it < 8; ++it)
        gl16(&clo[((size_t)b * SEQ + s0 + it * 16 + r_sub) * DIM + kc + c_sub], &Sl[it * 512]);
    } else if (wave == 2) {
#pragma unroll
      for (int it = 0; it < 8; ++it)
        gl16(&zhi[((size_t)(q0 + it * 16 + r_sub) * B_ + b) * DIM + kc + c_sub], &Qh[it * 512]);
    } else {
#pragma unroll
      for (int it = 0; it < 8; ++it)
        gl16(&zlo[((size_t)(q0 + it * 16 + r_sub) * B_ + b) * DIM + kc + c_sub], &Ql[it * 512]);
    }
    __syncthreads();

    short8 sh_[4], sl_[4], qh_[4], ql_[4];
#pragma unroll
    for (int f = 0; f < 4; ++f) {
      const int ra = wm + f * 16 + (lane & 15);
      const int rb = wn + f * 16 + (lane & 15);
      const int so = ra * 32 + (((lane >> 4) ^ ((ra >> 1) & 3))) * 8;
      const int qo = rb * 32 + (((lane >> 4) ^ ((rb >> 1) & 3))) * 8;
      sh_[f] = *(const short8*)&Sh[so];  sl_[f] = *(const short8*)&Sl[so];
      qh_[f] = *(const short8*)&Qh[qo];  ql_[f] = *(const short8*)&Ql[qo];
    }
#pragma unroll
    for (int i = 0; i < 4; ++i)
#pragma unroll
      for (int j = 0; j < 4; ++j) {
        acc[i][j] = __builtin_amdgcn_mfma_f32_16x16x32_bf16(sh_[i], qh_[j], acc[i][j], 0, 0, 0);
        acc[i][j] = __builtin_amdgcn_mfma_f32_16x16x32_bf16(sl_[i], qh_[j], acc[i][j], 0, 0, 0);
        acc[i][j] = __builtin_amdgcn_mfma_f32_16x16x32_bf16(sh_[i], ql_[j], acc[i][j], 0, 0, 0);
      }
    __syncthreads();
  }

#pragma unroll
  for (int i = 0; i < 4; ++i)
#pragma unroll
    for (int j = 0; j < 4; ++j) {
      const int s = s0 + wm + i * 16 + (lane >> 4) * 4;
      const int q = q0 + wn + j * 16 + (lane & 15);
      f32x4 v = {acc[i][j][0], acc[i][j][1], acc[i][j][2], acc[i][j][3]};
      __builtin_nontemporal_store(v, (f32x4*)&Sc[((size_t)q * B_ + b) * SEQ + s]);
    }
}

// ---------------------------------------------------------------------------
// softmax: in-place + bf16 side copy; f32 output stores NONTEMPORAL (never
// re-read on device -> keep L3 for attnb/ctxT which g3 consumes)
// ---------------------------------------------------------------------------
__global__ __launch_bounds__(256) void kernel_softmax(float* __restrict__ attn,
                                                      const int* __restrict__ mask,
                                                      unsigned short* __restrict__ attnb) {
  const int row = blockIdx.x;       // q*B_ + b
  const int b = row & (B_ - 1);
  const int q = row >> 4;
  float* p = attn + (size_t)row * SEQ;
  const int* m = mask + (size_t)b * SEQ;
  unsigned short* pb = attnb + ((size_t)b * SEQ + q) * SEQ;
  const int t = threadIdx.x;

  float4 va = *(const float4*)&p[t * 8];
  float4 vb = *(const float4*)&p[t * 8 + 4];
  int4 ma = *(const int4*)&m[t * 8];
  int4 mb = *(const int4*)&m[t * 8 + 4];
  float v[8] = {ma.x ? -1e30f : va.x, ma.y ? -1e30f : va.y,
                ma.z ? -1e30f : va.z, ma.w ? -1e30f : va.w,
                mb.x ? -1e30f : vb.x, mb.y ? -1e30f : vb.y,
                mb.z ? -1e30f : vb.z, mb.w ? -1e30f : vb.w};
  float mx = -INFINITY;
#pragma unroll
  for (int i = 0; i < 8; ++i) mx = fmaxf(mx, v[i]);
#pragma unroll
  for (int off = 32; off > 0; off >>= 1) mx = fmaxf(mx, __shfl_xor(mx, off));
  __shared__ float redmax[4];
  __shared__ float redsum[4];
  if ((t & 63) == 0) redmax[t >> 6] = mx;
  __syncthreads();
  mx = fmaxf(fmaxf(redmax[0], redmax[1]), fmaxf(redmax[2], redmax[3]));

  float sum = 0.f;
#pragma unroll
  for (int i = 0; i < 8; ++i) {
    v[i] = __expf(v[i] - mx);
    sum += v[i];
  }
#pragma unroll
  for (int off = 32; off > 0; off >>= 1) sum += __shfl_xor(sum, off);
  if ((t & 63) == 0) redsum[t >> 6] = sum;
  __syncthreads();
  sum = (redsum[0] + redsum[1]) + (redsum[2] + redsum[3]);

  const bool allmasked = (mx < -1e29f);
  const float inv = allmasked ? 0.f : 1.f / sum;
  float o[8];
  short8 ob16;
#pragma unroll
  for (int i = 0; i < 8; ++i) {
    o[i] = v[i] * inv;
    ob16[i] = (short)f2bf(o[i]);
  }
  f32x4 oa = {o[0], o[1], o[2], o[3]};
  f32x4 ob = {o[4], o[5], o[6], o[7]};
  __builtin_nontemporal_store(oa, (f32x4*)&p[t * 8]);
  __builtin_nontemporal_store(ob, (f32x4*)&p[t * 8 + 4]);
  *(short8*)&pb[t * 8] = ob16;     // re-read by g3 -> keep cached
}

// ---------------------------------------------------------------------------
// G3 (2-plane pure-gl16, BK=64, st_16x32, XCD-swizzled grid):
// comp[q][b][d] = sum_s attnb[b][q][s] * ctxT[b][d][s]
// ---------------------------------------------------------------------------
#define G3GRID 2048    // 8 d-tiles x 16 q-tiles x 16 batches
__global__ __launch_bounds__(256) void g3_comp(const unsigned short* __restrict__ attnb,
                                               const unsigned short* __restrict__ ctxT,
                                               float* __restrict__ Out) {
  __shared__ unsigned short Ad[128 * 64];   // ctxT tile (d-rows)
  __shared__ unsigned short Bq[128 * 64];   // attnb tile (q-rows)
  const int tid = threadIdx.x, lane = tid & 63, wave = tid >> 6;

  const int lin = blockIdx.x;
  const int swz = (lin & 7) * (G3GRID / 8) + (lin >> 3);
  const int b = swz >> 7;
  const int rem = swz & 127;
  const int d0 = (rem >> 4) * 128;   // 8 d-tiles
  const int q0 = (rem & 15) * 128;   // 16 q-tiles (fastest -> ctxT panel L2-resident)

  const int wm = (wave >> 1) * 64;   // d
  const int wn = (wave & 1) * 64;    // q

  const int r8 = lane >> 3;          // row within 8-row granule
  const int c8 = lane & 7;           // 16B block
  const unsigned short* src;
  if (wave < 2)
    src = ctxT + ((size_t)b * DIM + d0 + wave * 64 + r8) * SEQ + (size_t)((c8 ^ r8) * 8);
  else
    src = attnb + ((size_t)b * SEQ + q0 + (wave - 2) * 64 + r8) * SEQ + (size_t)((c8 ^ r8) * 8);
  unsigned short* ldst = (wave < 2) ? &Ad[wave * 64 * 64] : &Bq[(wave - 2) * 64 * 64];

  f32x4 acc[4][4];
#pragma unroll
  for (int i = 0; i < 4; ++i)
#pragma unroll
    for (int j = 0; j < 4; ++j) acc[i][j] = (f32x4){0.f, 0.f, 0.f, 0.f};

  for (int kc = 0; kc < SEQ; kc += 64) {
#pragma unroll
    for (int g = 0; g < 8; ++g)
      gl16(src + (size_t)g * 8 * SEQ + kc, ldst + g * 8 * 64);
    __syncthreads();

    short8 af[4][2], bf_[4][2];
#pragma unroll
    for (int f = 0; f < 4; ++f) {
      const int ra = wm + f * 16 + (lane & 15);
      const int rb = wn + f * 16 + (lane & 15);
#pragma unroll
      for (int h = 0; h < 2; ++h) {
        const int kb = h * 4 + (lane >> 4);
        af[f][h]  = *(const short8*)&Ad[ra * 64 + ((kb ^ (ra & 7))) * 8];
        bf_[f][h] = *(const short8*)&Bq[rb * 64 + ((kb ^ (rb & 7))) * 8];
      }
    }
#pragma unroll
    for (int i = 0; i < 4; ++i)
#pragma unroll
      for (int j = 0; j < 4; ++j) {
        acc[i][j] = __builtin_amdgcn_mfma_f32_16x16x32_bf16(af[i][0], bf_[j][0], acc[i][j], 0, 0, 0);
        acc[i][j] = __builtin_amdgcn_mfma_f32_16x16x32_bf16(af[i][1], bf_[j][1], acc[i][j], 0, 0, 0);
      }
    __syncthreads();
  }

#pragma unroll
  for (int i = 0; i < 4; ++i)
#pragma unroll
    for (int j = 0; j < 4; ++j) {
      const int d = d0 + wm + i * 16 + (lane >> 4) * 4;
      const int q = q0 + wn + j * 16 + (lane & 15);
      f32x4 v = {acc[i][j][0], acc[i][j][1], acc[i][j][2], acc[i][j][3]};
      __builtin_nontemporal_store(v, (f32x4*)&Out[((size_t)q * B_ + b) * DIM + d]);
    }
}

extern "C" void kernel_launch(void* const* d_in, const int* in_sizes, int n_in,
                              void* d_out, int out_size, void* d_ws, size_t ws_size,
                              hipStream_t stream) {
  const float* context = (const float*)d_in[0];   // [B, SEQ, DIM]
  const float* query   = (const float*)d_in[1];   // [SEQ, B, DIM]
  const float* W       = (const float*)d_in[2];   // [DIM, DIM]  ([d][e])
  const int*   mask    = (const int*)d_in[3];     // [B, SEQ] bool->int32

  float* attn = (float*)d_out;                     // [SEQ, B, SEQ]  (256 MiB)
  float* comp = attn + (size_t)SEQ * B_ * SEQ;     // [SEQ, B, DIM]  (128 MiB)

  // comp region: ctx hi/lo planes (dead after t_chi; g3 overwrites at end)
  unsigned short* chi = (unsigned short*)comp;                     // 64 MiB
  unsigned short* clo = chi + (size_t)B_ * SEQ * DIM;              // 64 MiB

  // attn region (free until g2 writes it): query hi/lo + W hi/lo planes
  unsigned short* qh = (unsigned short*)attn;                      // 64 MiB
  unsigned short* ql = qh + (size_t)SEQ * B_ * DIM;                // 64 MiB
  unsigned short* wh = ql + (size_t)SEQ * B_ * DIM;                // 2 MiB
  unsigned short* wl = wh + (size_t)DIM * DIM;                     // 2 MiB

  // ws: z hi/lo for g1->g2; then ctxT + attnb reuse it after g2
  unsigned short* zhi   = (unsigned short*)d_ws;                   // 64 MiB
  unsigned short* zlo   = zhi + (size_t)SEQ * B_ * DIM;            // 64 MiB
  unsigned short* ctxT  = (unsigned short*)d_ws;                   // 64 MiB (after g2)
  unsigned short* attnb = zlo;                                     // 64 MiB (after g2)

  // 0) splits
  cvt_split<<<dim3(4096), 256, 0, stream>>>(context, chi, clo);
  cvt_split<<<dim3(4096), 256, 0, stream>>>(query, qh, ql);
  cvt_w<<<dim3(512), 256, 0, stream>>>(W, wh, wl);
  // 1) z = q . W-rows (m97-clone, pure gl16)
  g1_z<<<dim3(G1GRID), 256, 0, stream>>>(qh, ql, wh, wl, zhi, zlo);
  // 2) scores -> attn region (clobbers qh/ql/wh/wl, now dead)
  g2_scores<<<dim3(G2GRID), 256, 0, stream>>>(zhi, zlo, chi, clo, attn);
  // 2b) ctxT = transpose(chi) into ws (z dead after g2)
  t_chi<<<dim3(DIM / 64, SEQ / 64, B_), 256, 0, stream>>>(chi, ctxT);
  // 3) masked softmax in place (NT f32 stores) + bf16 side copy into ws
  kernel_softmax<<<dim3(SEQ * B_), 256, 0, stream>>>(attn, mask, attnb);
  // 4) comp = attnb . ctxT (2-plane pure gl16, BK=64, XCD swizzle)
  g3_comp<<<dim3(G3GRID), 256, 0, stream>>>(attnb, ctxT, comp);
}

// Round 15
// 1106.267 us; speedup vs baseline: 1.0234x; 1.0234x over previous
//
#include <hip/hip_runtime.h>
#include <cmath>

#define B_  16
#define SEQ 2048
#define DIM 1024

typedef short  short8 __attribute__((ext_vector_type(8)));
typedef short  sh4    __attribute__((ext_vector_type(4)));
typedef float  f32x4  __attribute__((ext_vector_type(4)));

__device__ __forceinline__ unsigned short f2bf(float x) {
  unsigned u = __builtin_bit_cast(unsigned, x);
  return (unsigned short)((u + 0x7fffu + ((u >> 16) & 1u)) >> 16);   // RNE
}
__device__ __forceinline__ float bf2f(unsigned short h) {
  unsigned u = ((unsigned)h) << 16;
  return __builtin_bit_cast(float, u);
}

__device__ __forceinline__ void gl16(const void* g, void* l) {
  __builtin_amdgcn_global_load_lds(
      (const __attribute__((address_space(1))) void*)g,
      (__attribute__((address_space(3))) void*)l, 16, 0, 0);
}

// ---------------------------------------------------------------------------
// cvt_split: f32 [B*SEQ*DIM] -> bf16 hi/lo planes (context AND query)
// ---------------------------------------------------------------------------
__global__ __launch_bounds__(256) void cvt_split(const float* __restrict__ X,
                                                 unsigned short* __restrict__ hi,
                                                 unsigned short* __restrict__ lo) {
  const size_t N8 = (size_t)B_ * SEQ * DIM / 8;
  for (size_t i = (size_t)blockIdx.x * 256 + threadIdx.x; i < N8;
       i += (size_t)gridDim.x * 256) {
    const size_t base = i * 8;
    float4 a = *(const float4*)&X[base];
    float4 c = *(const float4*)&X[base + 4];
    const float xs[8] = {a.x, a.y, a.z, a.w, c.x, c.y, c.z, c.w};
    short8 h, l;
#pragma unroll
    for (int j = 0; j < 8; ++j) {
      unsigned short hh = f2bf(xs[j]);
      h[j] = (short)hh;
      l[j] = (short)f2bf(xs[j] - bf2f(hh));
    }
    *(short8*)&hi[base] = h;
    *(short8*)&lo[base] = l;
  }
}

// ---------------------------------------------------------------------------
// cvt_w: W[d][e] f32 -> wh[d][e], wl[d][e] bf16 hi/lo (pure split)
// ---------------------------------------------------------------------------
__global__ __launch_bounds__(256) void cvt_w(const float* __restrict__ X,
                                             unsigned short* __restrict__ hi,
                                             unsigned short* __restrict__ lo) {
  const size_t N8 = (size_t)DIM * DIM / 8;
  for (size_t i = (size_t)blockIdx.x * 256 + threadIdx.x; i < N8;
       i += (size_t)gridDim.x * 256) {
    const size_t base = i * 8;
    float4 a = *(const float4*)&X[base];
    float4 c = *(const float4*)&X[base + 4];
    const float xs[8] = {a.x, a.y, a.z, a.w, c.x, c.y, c.z, c.w};
    short8 h, l;
#pragma unroll
    for (int j = 0; j < 8; ++j) {
      unsigned short hh = f2bf(xs[j]);
      h[j] = (short)hh;
      l[j] = (short)f2bf(xs[j] - bf2f(hh));
    }
    *(short8*)&hi[base] = h;
    *(short8*)&lo[base] = l;
  }
}

// ---------------------------------------------------------------------------
// t_chi: ctxT[b][d][s] = transpose of chi[b][s][d]  (bf16 -> bf16, via LDS)
// ---------------------------------------------------------------------------
__global__ __launch_bounds__(256) void t_chi(const unsigned short* __restrict__ H,
                                             unsigned short* __restrict__ T) {
  __shared__ unsigned short L[64][72];
  const int t = threadIdx.x;
  const int d0 = blockIdx.x * 64, s0 = blockIdx.y * 64, b = blockIdx.z;
  const int sl = t >> 2, dp = (t & 3) * 16;
  short8 v0 = *(const short8*)&H[((size_t)b * SEQ + s0 + sl) * DIM + d0 + dp];
  short8 v1 = *(const short8*)&H[((size_t)b * SEQ + s0 + sl) * DIM + d0 + dp + 8];
  *(short8*)&L[sl][dp] = v0;
  *(short8*)&L[sl][dp + 8] = v1;
  __syncthreads();
  const int dl = t >> 2, sp = (t & 3) * 16;
  short8 o0, o1;
#pragma unroll
  for (int k = 0; k < 8; ++k) {
    o0[k] = (short)L[sp + k][dl];
    o1[k] = (short)L[sp + 8 + k][dl];
  }
  *(short8*)&T[((size_t)b * DIM + d0 + dl) * SEQ + s0 + sp] = o0;
  *(short8*)&T[((size_t)b * DIM + d0 + dl) * SEQ + s0 + sp + 8] = o1;
}

// ---------------------------------------------------------------------------
// G1 (m97-clone): z[r][d] = sum_e q[r][e] * W[d][e], 4 planes pure-gl16.
// ---------------------------------------------------------------------------
#define G1GRID 2048    // 256 m-tiles x 8 n-tiles
__global__ __launch_bounds__(256) void g1_z(const unsigned short* __restrict__ qh,
                                            const unsigned short* __restrict__ ql,
                                            const unsigned short* __restrict__ wh,
                                            const unsigned short* __restrict__ wl,
                                            unsigned short* __restrict__ zhi,
                                            unsigned short* __restrict__ zlo) {
  __shared__ unsigned short Ah[128 * 32], Al[128 * 32];
  __shared__ unsigned short Bh[128 * 32], Bl[128 * 32];
  const int tid = threadIdx.x, lane = tid & 63, wave = tid >> 6;

  const int lin = blockIdx.x;
  const int swz = (lin & 7) * (G1GRID / 8) + (lin >> 3);
  const int m0 = (swz >> 3) * 128;
  const int n0 = (swz & 7) * 128;

  const int wm = (wave >> 1) * 64;   // m (z-row)
  const int wn = (wave & 1) * 64;    // n (d)

  const int r_sub = lane >> 2;
  const int c_sub = (((lane & 3) ^ ((lane >> 3) & 3))) * 8;

  f32x4 acc[4][4];
#pragma unroll
  for (int i = 0; i < 4; ++i)
#pragma unroll
    for (int j = 0; j < 4; ++j) acc[i][j] = (f32x4){0.f, 0.f, 0.f, 0.f};

  for (int kc = 0; kc < DIM; kc += 32) {
    if (wave == 0) {
#pragma unroll
      for (int it = 0; it < 8; ++it)
        gl16(&qh[(size_t)(m0 + it * 16 + r_sub) * DIM + kc + c_sub], &Ah[it * 512]);
    } else if (wave == 1) {
#pragma unroll
      for (int it = 0; it < 8; ++it)
        gl16(&ql[(size_t)(m0 + it * 16 + r_sub) * DIM + kc + c_sub], &Al[it * 512]);
    } else if (wave == 2) {
#pragma unroll
      for (int it = 0; it < 8; ++it)
        gl16(&wh[(size_t)(n0 + it * 16 + r_sub) * DIM + kc + c_sub], &Bh[it * 512]);
    } else {
#pragma unroll
      for (int it = 0; it < 8; ++it)
        gl16(&wl[(size_t)(n0 + it * 16 + r_sub) * DIM + kc + c_sub], &Bl[it * 512]);
    }
    __syncthreads();

    short8 ah[4], al[4], bh[4], bl[4];
#pragma unroll
    for (int f = 0; f < 4; ++f) {
      const int ra = wm + f * 16 + (lane & 15);
      const int rb = wn + f * 16 + (lane & 15);
      const int ao = ra * 32 + (((lane >> 4) ^ ((ra >> 1) & 3))) * 8;
      const int bo = rb * 32 + (((lane >> 4) ^ ((rb >> 1) & 3))) * 8;
      ah[f] = *(const short8*)&Ah[ao];  al[f] = *(const short8*)&Al[ao];
      bh[f] = *(const short8*)&Bh[bo];  bl[f] = *(const short8*)&Bl[bo];
    }
#pragma unroll
    for (int i = 0; i < 4; ++i)
#pragma unroll
      for (int j = 0; j < 4; ++j) {
        acc[i][j] = __builtin_amdgcn_mfma_f32_16x16x32_bf16(ah[i], bh[j], acc[i][j], 0, 0, 0);
        acc[i][j] = __builtin_amdgcn_mfma_f32_16x16x32_bf16(al[i], bh[j], acc[i][j], 0, 0, 0);
        acc[i][j] = __builtin_amdgcn_mfma_f32_16x16x32_bf16(ah[i], bl[j], acc[i][j], 0, 0, 0);
      }
    __syncthreads();
  }

#pragma unroll
  for (int i = 0; i < 4; ++i)
#pragma unroll
    for (int j = 0; j < 4; ++j)
#pragma unroll
      for (int r = 0; r < 4; ++r) {
        const int row = m0 + wm + i * 16 + (lane >> 4) * 4 + r;
        const int col = n0 + wn + j * 16 + (lane & 15);
        const float v = acc[i][j][r];
        const unsigned short h = f2bf(v);
        zhi[(size_t)row * DIM + col] = h;
        zlo[(size_t)row * DIM + col] = f2bf(v - bf2f(h));
      }
}

// ---------------------------------------------------------------------------
// G2 (R6-proven, 128x128, 2-barrier, XOR-swizzled): scores = z . ctx^T
// ---------------------------------------------------------------------------
#define G2GRID (16 * 16 * B_)
__global__ __launch_bounds__(256) void g2_scores(const unsigned short* __restrict__ zhi,
                                                 const unsigned short* __restrict__ zlo,
                                                 const unsigned short* __restrict__ chi,
                                                 const unsigned short* __restrict__ clo,
                                                 float* __restrict__ Sc) {
  __shared__ unsigned short Sh[128 * 32], Sl[128 * 32];   // ctx tiles (s-rows)
  __shared__ unsigned short Qh[128 * 32], Ql[128 * 32];   // z tiles (q-rows)
  const int tid = threadIdx.x, lane = tid & 63, wave = tid >> 6;

  const int lin = blockIdx.x;
  const int swz = (lin & 7) * (G2GRID / 8) + (lin >> 3);
  const int s0 = (swz & 15) * 128;
  const int q0 = ((swz >> 4) & 15) * 128;
  const int b  = swz >> 8;

  const int wm = (wave >> 1) * 64;   // s
  const int wn = (wave & 1) * 64;    // q

  const int r_sub = lane >> 2;
  const int c_sub = (((lane & 3) ^ ((lane >> 3) & 3))) * 8;

  f32x4 acc[4][4];
#pragma unroll
  for (int i = 0; i < 4; ++i)
#pragma unroll
    for (int j = 0; j < 4; ++j) acc[i][j] = (f32x4){0.f, 0.f, 0.f, 0.f};

  for (int kc = 0; kc < DIM; kc += 32) {
    if (wave == 0) {
#pragma unroll
      for (int it = 0; it < 8; ++it)
        gl16(&chi[((size_t)b * SEQ + s0 + it * 16 + r_sub) * DIM + kc + c_sub], &Sh[it * 512]);
    } else if (wave == 1) {
#pragma unroll
      for (int it = 0; it < 8; ++it)
        gl16(&clo[((size_t)b * SEQ + s0 + it * 16 + r_sub) * DIM + kc + c_sub], &Sl[it * 512]);
    } else if (wave == 2) {
#pragma unroll
      for (int it = 0; it < 8; ++it)
        gl16(&zhi[((size_t)(q0 + it * 16 + r_sub) * B_ + b) * DIM + kc + c_sub], &Qh[it * 512]);
    } else {
#pragma unroll
      for (int it = 0; it < 8; ++it)
        gl16(&zlo[((size_t)(q0 + it * 16 + r_sub) * B_ + b) * DIM + kc + c_sub], &Ql[it * 512]);
    }
    __syncthreads();

    short8 sh_[4], sl_[4], qh_[4], ql_[4];
#pragma unroll
    for (int f = 0; f < 4; ++f) {
      const int ra = wm + f * 16 + (lane & 15);
      const int rb = wn + f * 16 + (lane & 15);
      const int so = ra * 32 + (((lane >> 4) ^ ((ra >> 1) & 3))) * 8;
      const int qo = rb * 32 + (((lane >> 4) ^ ((rb >> 1) & 3))) * 8;
      sh_[f] = *(const short8*)&Sh[so];  sl_[f] = *(const short8*)&Sl[so];
      qh_[f] = *(const short8*)&Qh[qo];  ql_[f] = *(const short8*)&Ql[qo];
    }
#pragma unroll
    for (int i = 0; i < 4; ++i)
#pragma unroll
      for (int j = 0; j < 4; ++j) {
        acc[i][j] = __builtin_amdgcn_mfma_f32_16x16x32_bf16(sh_[i], qh_[j], acc[i][j], 0, 0, 0);
        acc[i][j] = __builtin_amdgcn_mfma_f32_16x16x32_bf16(sl_[i], qh_[j], acc[i][j], 0, 0, 0);
        acc[i][j] = __builtin_amdgcn_mfma_f32_16x16x32_bf16(sh_[i], ql_[j], acc[i][j], 0, 0, 0);
      }
    __syncthreads();
  }

#pragma unroll
  for (int i = 0; i < 4; ++i)
#pragma unroll
    for (int j = 0; j < 4; ++j) {
      const int s = s0 + wm + i * 16 + (lane >> 4) * 4;
      const int q = q0 + wn + j * 16 + (lane & 15);
      f32x4 v = {acc[i][j][0], acc[i][j][1], acc[i][j][2], acc[i][j][3]};
      __builtin_nontemporal_store(v, (f32x4*)&Sc[((size_t)q * B_ + b) * SEQ + s]);
    }
}

// ---------------------------------------------------------------------------
// softmax: in-place + bf16 side copy to attnb[b][q][s]  (regular stores)
// ---------------------------------------------------------------------------
__global__ __launch_bounds__(256) void kernel_softmax(float* __restrict__ attn,
                                                      const int* __restrict__ mask,
                                                      unsigned short* __restrict__ attnb) {
  const int row = blockIdx.x;       // q*B_ + b
  const int b = row & (B_ - 1);
  const int q = row >> 4;
  float* p = attn + (size_t)row * SEQ;
  const int* m = mask + (size_t)b * SEQ;
  unsigned short* pb = attnb + ((size_t)b * SEQ + q) * SEQ;
  const int t = threadIdx.x;

  float4 va = *(const float4*)&p[t * 8];
  float4 vb = *(const float4*)&p[t * 8 + 4];
  int4 ma = *(const int4*)&m[t * 8];
  int4 mb = *(const int4*)&m[t * 8 + 4];
  float v[8] = {ma.x ? -1e30f : va.x, ma.y ? -1e30f : va.y,
                ma.z ? -1e30f : va.z, ma.w ? -1e30f : va.w,
                mb.x ? -1e30f : vb.x, mb.y ? -1e30f : vb.y,
                mb.z ? -1e30f : vb.z, mb.w ? -1e30f : vb.w};
  float mx = -INFINITY;
#pragma unroll
  for (int i = 0; i < 8; ++i) mx = fmaxf(mx, v[i]);
#pragma unroll
  for (int off = 32; off > 0; off >>= 1) mx = fmaxf(mx, __shfl_xor(mx, off));
  __shared__ float redmax[4];
  __shared__ float redsum[4];
  if ((t & 63) == 0) redmax[t >> 6] = mx;
  __syncthreads();
  mx = fmaxf(fmaxf(redmax[0], redmax[1]), fmaxf(redmax[2], redmax[3]));

  float sum = 0.f;
#pragma unroll
  for (int i = 0; i < 8; ++i) {
    v[i] = __expf(v[i] - mx);
    sum += v[i];
  }
#pragma unroll
  for (int off = 32; off > 0; off >>= 1) sum += __shfl_xor(sum, off);
  if ((t & 63) == 0) redsum[t >> 6] = sum;
  __syncthreads();
  sum = (redsum[0] + redsum[1]) + (redsum[2] + redsum[3]);

  const bool allmasked = (mx < -1e29f);
  const float inv = allmasked ? 0.f : 1.f / sum;
  float o[8];
  short8 ob16;
#pragma unroll
  for (int i = 0; i < 8; ++i) {
    o[i] = v[i] * inv;
    ob16[i] = (short)f2bf(o[i]);
  }
  float4 oa = {o[0], o[1], o[2], o[3]};
  float4 ob = {o[4], o[5], o[6], o[7]};
  *(float4*)&p[t * 8] = oa;
  *(float4*)&p[t * 8 + 4] = ob;
  *(short8*)&pb[t * 8] = ob16;
}

// ---------------------------------------------------------------------------
// G3 (2-plane pure-gl16, BK=64, st_16x32): comp[q][b][d] = sum_s attnb*ctxT
// A = ctxT d-rows, B = attnb q-rows, both staged via gl16 with pre-swizzled
// source block (L[r][blk] = G[r][blk^(r&7)]); frag read blk = kb^(r&7).
// ---------------------------------------------------------------------------
__global__ __launch_bounds__(256) void g3_comp(const unsigned short* __restrict__ attnb,
                                               const unsigned short* __restrict__ ctxT,
                                               float* __restrict__ Out) {
  __shared__ unsigned short Ad[128 * 64];   // ctxT tile (d-rows)
  __shared__ unsigned short Bq[128 * 64];   // attnb tile (q-rows)
  const int tid = threadIdx.x, lane = tid & 63, wave = tid >> 6;
  const int b = blockIdx.z;
  const int d0 = blockIdx.x * 128, q0 = blockIdx.y * 128;
  const int wm = (wave >> 1) * 64;   // d
  const int wn = (wave & 1) * 64;    // q

  const int r8 = lane >> 3;          // row within 8-row granule
  const int c8 = lane & 7;           // 16B block
  const unsigned short* src;
  if (wave < 2)
    src = ctxT + ((size_t)b * DIM + d0 + wave * 64 + r8) * SEQ + (size_t)((c8 ^ r8) * 8);
  else
    src = attnb + ((size_t)b * SEQ + q0 + (wave - 2) * 64 + r8) * SEQ + (size_t)((c8 ^ r8) * 8);
  unsigned short* ldst = (wave < 2) ? &Ad[wave * 64 * 64] : &Bq[(wave - 2) * 64 * 64];

  f32x4 acc[4][4];
#pragma unroll
  for (int i = 0; i < 4; ++i)
#pragma unroll
    for (int j = 0; j < 4; ++j) acc[i][j] = (f32x4){0.f, 0.f, 0.f, 0.f};

  for (int kc = 0; kc < SEQ; kc += 64) {
#pragma unroll
    for (int g = 0; g < 8; ++g)
      gl16(src + (size_t)g * 8 * SEQ + kc, ldst + g * 8 * 64);
    __syncthreads();

    short8 af[4][2], bf_[4][2];
#pragma unroll
    for (int f = 0; f < 4; ++f) {
      const int ra = wm + f * 16 + (lane & 15);
      const int rb = wn + f * 16 + (lane & 15);
#pragma unroll
      for (int h = 0; h < 2; ++h) {
        const int kb = h * 4 + (lane >> 4);
        af[f][h]  = *(const short8*)&Ad[ra * 64 + ((kb ^ (ra & 7))) * 8];
        bf_[f][h] = *(const short8*)&Bq[rb * 64 + ((kb ^ (rb & 7))) * 8];
      }
    }
#pragma unroll
    for (int i = 0; i < 4; ++i)
#pragma unroll
      for (int j = 0; j < 4; ++j) {
        acc[i][j] = __builtin_amdgcn_mfma_f32_16x16x32_bf16(af[i][0], bf_[j][0], acc[i][j], 0, 0, 0);
        acc[i][j] = __builtin_amdgcn_mfma_f32_16x16x32_bf16(af[i][1], bf_[j][1], acc[i][j], 0, 0, 0);
      }
    __syncthreads();
  }

#pragma unroll
  for (int i = 0; i < 4; ++i)
#pragma unroll
    for (int j = 0; j < 4; ++j) {
      const int d = d0 + wm + i * 16 + (lane >> 4) * 4;
      const int q = q0 + wn + j * 16 + (lane & 15);
      f32x4 v = {acc[i][j][0], acc[i][j][1], acc[i][j][2], acc[i][j][3]};
      __builtin_nontemporal_store(v, (f32x4*)&Out[((size_t)q * B_ + b) * DIM + d]);
    }
}

extern "C" void kernel_launch(void* const* d_in, const int* in_sizes, int n_in,
                              void* d_out, int out_size, void* d_ws, size_t ws_size,
                              hipStream_t stream) {
  const float* context = (const float*)d_in[0];   // [B, SEQ, DIM]
  const float* query   = (const float*)d_in[1];   // [SEQ, B, DIM]
  const float* W       = (const float*)d_in[2];   // [DIM, DIM]  ([d][e])
  const int*   mask    = (const int*)d_in[3];     // [B, SEQ] bool->int32

  float* attn = (float*)d_out;                     // [SEQ, B, SEQ]  (256 MiB)
  float* comp = attn + (size_t)SEQ * B_ * SEQ;     // [SEQ, B, DIM]  (128 MiB)

  // comp region: ctx hi/lo planes (dead after t_chi; g3 overwrites at end)
  unsigned short* chi = (unsigned short*)comp;                     // 64 MiB
  unsigned short* clo = chi + (size_t)B_ * SEQ * DIM;              // 64 MiB

  // attn region (free until g2 writes it): query hi/lo + W hi/lo planes
  unsigned short* qh = (unsigned short*)attn;                      // 64 MiB
  unsigned short* ql = qh + (size_t)SEQ * B_ * DIM;                // 64 MiB
  unsigned short* wh = ql + (size_t)SEQ * B_ * DIM;                // 2 MiB
  unsigned short* wl = wh + (size_t)DIM * DIM;                     // 2 MiB

  // ws: z hi/lo for g1->g2; then ctxT + attnb reuse it after g2
  unsigned short* zhi   = (unsigned short*)d_ws;                   // 64 MiB
  unsigned short* zlo   = zhi + (size_t)SEQ * B_ * DIM;            // 64 MiB
  unsigned short* ctxT  = (unsigned short*)d_ws;                   // 64 MiB (after g2)
  unsigned short* attnb = zlo;                                     // 64 MiB (after g2)

  // 0) splits
  cvt_split<<<dim3(4096), 256, 0, stream>>>(context, chi, clo);
  cvt_split<<<dim3(4096), 256, 0, stream>>>(query, qh, ql);
  cvt_w<<<dim3(512), 256, 0, stream>>>(W, wh, wl);
  // 1) z = q . W-rows (m97-clone, pure gl16)
  g1_z<<<dim3(G1GRID), 256, 0, stream>>>(qh, ql, wh, wl, zhi, zlo);
  // 2) scores -> attn region (clobbers qh/ql/wh/wl, now dead)
  g2_scores<<<dim3(G2GRID), 256, 0, stream>>>(zhi, zlo, chi, clo, attn);
  // 2b) ctxT = transpose(chi) into ws (z dead after g2)
  t_chi<<<dim3(DIM / 64, SEQ / 64, B_), 256, 0, stream>>>(chi, ctxT);
  // 3) masked softmax in place + bf16 side copy into ws
  kernel_softmax<<<dim3(SEQ * B_), 256, 0, stream>>>(attn, mask, attnb);
  // 4) comp = attnb . ctxT (2-plane pure gl16, BK=64)
  g3_comp<<<dim3(DIM / 128, SEQ / 128, B_), 256, 0, stream>>>(attnb, ctxT, comp);
}